// Round 18
// baseline (58.909 us; speedup 1.0000x reference)
//
#include <hip/hip_runtime.h>
#include <hip/hip_bf16.h>
#include <hip/hip_fp16.h>
#include <math.h>

#define T_TOKENS 16384
#define DDIM 2048
#define NEXP 64
#define REFINE_TAU 4e-3f
#define NCHK 16                    // 16 chunks of 128 k
#define BLK_TOK 32
#define NBLK (T_TOKENS / BLK_TOK)  // 512 blocks, 32 tokens each

typedef _Float16 f16x8 __attribute__((ext_vector_type(8)));
typedef float f32x4 __attribute__((ext_vector_type(4)));

__device__ __forceinline__ void gload_lds16(const void* g, void* l) {
    __builtin_amdgcn_global_load_lds(
        (const __attribute__((address_space(1))) void*)g,
        (__attribute__((address_space(3))) void*)l, 16, 0, 0);
}

// ---------------- Kernel 0: W fp32 -> fp16 fragment-ordered panel ----------------
// (r,k) -> pw[((g*64 + ks)*64 + lane)*8 + j], g=r>>4, ks=k>>5,
// lane=((k>>3)&3)*16 + (r&15), j=k&7.  (A-frag mapping, verified R4-R17.)
__global__ __launch_bounds__(256)
void prep_w(const float* __restrict__ W, _Float16* __restrict__ pw) {
    const int t  = blockIdx.x * 256 + threadIdx.x;   // 0..16383
    const int r  = t >> 8;
    const int kc = (t & 255) * 8;
    const float* wp = &W[(size_t)r * DDIM + kc];
    const float4 a = *(const float4*)wp;
    const float4 b = *(const float4*)(wp + 4);
    const float f[8] = { a.x, a.y, a.z, a.w, b.x, b.y, b.z, b.w };
    f16x8 h;
#pragma unroll
    for (int j = 0; j < 8; ++j) h[j] = (_Float16)f[j];
    const int g = r >> 4, ks = kc >> 5;
    const int lane = (((kc >> 3) & 3) << 4) + (r & 15);
    *(f16x8*)&pw[(((size_t)g * 64 + ks) * 64 + lane) * 8] = h;
}

// ---------------- Kernel 1: 32-token LDS-staged gate + fused top-2 ----------------
__device__ __forceinline__ bool better(double va, int ia, double vb, int ib) {
    return (va > vb) || (va == vb && ia < ib);
}

// fast wave-cooperative f64 dot (R16-verified)
__device__ __forceinline__ double dot_f64_fast(const float* __restrict__ xrow,
                                               const float* __restrict__ wr, int lane) {
    float4 xa[8], wa[8];
#pragma unroll
    for (int q = 0; q < 8; ++q) {
        xa[q] = *(const float4*)&xrow[q * 256 + lane * 4];
        wa[q] = *(const float4*)&wr[q * 256 + lane * 4];
    }
    double s0 = 0.0, s1 = 0.0, s2 = 0.0, s3 = 0.0;
#pragma unroll
    for (int q = 0; q < 8; ++q) {
        s0 = fma((double)xa[q].x, (double)wa[q].x, s0);
        s1 = fma((double)xa[q].y, (double)wa[q].y, s1);
        s2 = fma((double)xa[q].z, (double)wa[q].z, s2);
        s3 = fma((double)xa[q].w, (double)wa[q].w, s3);
    }
    double sd = (s0 + s1) + (s2 + s3);
#pragma unroll
    for (int off = 32; off >= 1; off >>= 1) sd += __shfl_xor(sd, off);
    return sd;
}

// stage chunk c into xa[buf]: wave w covers rows 4w..4w+3 (of 32), two 1KB issues.
// Source col pre-swizzled (verified R17 involution): LDS linear, read applies XOR.
#define STAGE(buf, c) do { \
    gload_lds16(xs0 + (size_t)(c) * 512, (char*)&xa[buf][0] + (4 * w)     * 512); \
    gload_lds16(xs1 + (size_t)(c) * 512, (char*)&xa[buf][0] + (4 * w + 2) * 512); \
} while (0)

// panel frags for chunk c (4 ksteps) for expert group eg, contiguous 1KB wave-loads
#define LOADP(buf, c) do { \
    _Pragma("unroll") \
    for (int ks_ = 0; ks_ < 4; ++ks_) \
        pan[buf][ks_] = *(const f16x8*)&pw[(((size_t)eg * 64 + (c) * 4 + ks_) * 64 + lane) * 8]; \
} while (0)

// compute chunk from xa[buf]: 4 ksteps x 1 MFMA (16 tok x 16 exp per wave)
#define COMPUTE(buf) do { \
    _Pragma("unroll") \
    for (int ks_ = 0; ks_ < 4; ++ks_) { \
        const int col_ = ks_ * 128 + ((lane >> 4) << 5); \
        const f32x4 v0_ = *(const f32x4*)((const char*)&xa[buf][0] + rbase + ((col_)      ^ rswz)); \
        const f32x4 v1_ = *(const f32x4*)((const char*)&xa[buf][0] + rbase + ((col_ + 16) ^ rswz)); \
        f16x8 af_; \
        af_[0] = (_Float16)v0_[0]; af_[1] = (_Float16)v0_[1]; \
        af_[2] = (_Float16)v0_[2]; af_[3] = (_Float16)v0_[3]; \
        af_[4] = (_Float16)v1_[0]; af_[5] = (_Float16)v1_[1]; \
        af_[6] = (_Float16)v1_[2]; af_[7] = (_Float16)v1_[3]; \
        acc = __builtin_amdgcn_mfma_f32_16x16x32_f16(pan[buf][ks_], af_, acc, 0, 0, 0); \
    } \
} while (0)

__global__ __launch_bounds__(512)
void gate_fused(const float* __restrict__ x,
                const _Float16* __restrict__ pw,
                const float* __restrict__ W,
                float* __restrict__ out) {
    __shared__ float xa[2][4096];     // 2 x 16 KB: 32 rows x 512B, swizzled content
    __shared__ float lg[BLK_TOK][68]; // logits [token][expert], padded

    const int tid  = threadIdx.x;
    const int lane = tid & 63;
    const int w    = tid >> 6;        // 0..7
    const int tg   = w >> 2;          // token group (16 tokens)
    const int eg   = w & 3;           // expert group (16 experts)
    const int tokb = blockIdx.x * BLK_TOK;

    // ---- staging source (per-lane, pre-swizzled column; rows 4w..4w+3) ----
    const int r0 = 4 * w + (lane >> 5);
    const int r1 = 4 * w + 2 + (lane >> 5);
    const int v0 = ((lane & 31) * 16) ^ ((r0 & 7) << 4);
    const int v1 = ((lane & 31) * 16) ^ ((r1 & 7) << 4);
    const char* xs0 = (const char*)x + (size_t)(tokb + r0) * (DDIM * 4) + v0;
    const char* xs1 = (const char*)x + (size_t)(tokb + r1) * (DDIM * 4) + v1;

    // ---- frag-read geometry: row = tg*16 + (lane&15); (row&7) == (lane&7) ----
    const int rbase = (tg * 16 + (lane & 15)) * 512;
    const int rswz  = (lane & 7) << 4;

    f16x8 pan[2][4];
    f32x4 acc = { 0.f, 0.f, 0.f, 0.f };

    STAGE(0, 0);
    LOADP(0, 0);
    __syncthreads();                       // chunk 0 landed

#pragma unroll
    for (int c = 0; c < NCHK; ++c) {
        if (c + 1 < NCHK) {
            STAGE((c + 1) & 1, c + 1);     // direct-to-LDS, zero VGPR involvement
            LOADP((c + 1) & 1, c + 1);     // L2 panel frags for next chunk
        }
        COMPUTE(c & 1);
        __syncthreads();
    }

    // ---- logits -> LDS (C layout verified: token=lane&15 (+tg*16), expert=(lane>>4)*4+j (+eg*16)) ----
    *(f32x4*)&lg[tg * 16 + (lane & 15)][eg * 16 + ((lane >> 4) << 2)] = acc;
    __syncthreads();

    // ---- fused epilogue: wave w owns 4 tokens (verified structure + fast refine) ----
    float* __restrict__ outw = out;
    float* __restrict__ outi = out + (size_t)T_TOKENS * 2;

#pragma unroll 1
    for (int t = 0; t < 4; ++t) {
        const int lt  = w * 4 + t;
        const int tok = tokb + lt;
        const float l = lg[lt][lane];

        float v1v = l; int i1 = lane;
#pragma unroll
        for (int off = 32; off >= 1; off >>= 1) {
            const float ov = __shfl_xor(v1v, off);
            const int   oi = __shfl_xor(i1, off);
            if (ov > v1v || (ov == v1v && oi < i1)) { v1v = ov; i1 = oi; }
        }
        float v2v = (lane == i1) ? -INFINITY : l; int i2 = lane;
#pragma unroll
        for (int off = 32; off >= 1; off >>= 1) {
            const float ov = __shfl_xor(v2v, off);
            const int   oi = __shfl_xor(i2, off);
            if (ov > v2v || (ov == v2v && oi < i2)) { v2v = ov; i2 = oi; }
        }
        float v3v = (lane == i1 || lane == i2) ? -INFINITY : l; int i3 = lane;
#pragma unroll
        for (int off = 32; off >= 1; off >>= 1) {
            const float ov = __shfl_xor(v3v, off);
            const int   oi = __shfl_xor(i3, off);
            if (ov > v3v || (ov == v3v && oi < i3)) { v3v = ov; i3 = oi; }
        }

        const float p = expf(l - v1v);
        float s = p;
#pragma unroll
        for (int off = 32; off >= 1; off >>= 1) s += __shfl_xor(s, off);

        int iA = i1, iB = i2;
        if ((v1v - v2v) < REFINE_TAU || (v2v - v3v) < REFINE_TAU) {
            const float* __restrict__ xrow = x + (size_t)tok * DDIM;
            double La = dot_f64_fast(xrow, W + (size_t)i1 * DDIM, lane);
            double Lb = dot_f64_fast(xrow, W + (size_t)i2 * DDIM, lane);
            double Lc = dot_f64_fast(xrow, W + (size_t)i3 * DDIM, lane);
            int ia = i1, ib = i2, ic = i3;
            if (!better(La, ia, Lb, ib)) { double tv = La; La = Lb; Lb = tv; int ti = ia; ia = ib; ib = ti; }
            if (!better(Lb, ib, Lc, ic)) { double tv = Lb; Lb = Lc; Lc = tv; int ti = ib; ib = ic; ic = ti; }
            if (!better(La, ia, Lb, ib)) { double tv = La; La = Lb; Lb = tv; int ti = ia; ia = ib; ib = ti; }
            iA = ia; iB = ib;
        }

        const float pA = __shfl(p, iA);
        const float pB = __shfl(p, iB);
        const float pa_ = pA / s;
        const float pb_ = pB / s;
        const float inv = 1.0f / (pa_ + pb_ + 1e-9f);

        if (lane == 0) {
            const size_t tg2 = (size_t)tok;
            outw[tg2 * 2]     = pa_ * inv;
            outw[tg2 * 2 + 1] = pb_ * inv;
            outi[tg2 * 2]     = (float)iA;
            outi[tg2 * 2 + 1] = (float)iB;
        }
    }
}

extern "C" void kernel_launch(void* const* d_in, const int* in_sizes, int n_in,
                              void* d_out, int out_size, void* d_ws, size_t ws_size,
                              hipStream_t stream) {
    const float* x = (const float*)d_in[0];
    const float* W = (const float*)d_in[1];
    float* out = (float*)d_out;
    _Float16* pw = (_Float16*)d_ws;                 // 256 KB fp16 frag panel

    prep_w<<<NEXP * DDIM / 8 / 256, 256, 0, stream>>>(W, pw);
    gate_fused<<<NBLK, 512, 0, stream>>>(x, pw, W, out);
}

// Round 20
// 53.853 us; speedup vs baseline: 1.0939x; 1.0939x over previous
//
#include <hip/hip_runtime.h>
#include <hip/hip_bf16.h>
#include <hip/hip_fp16.h>
#include <math.h>

#define T_TOKENS 16384
#define DDIM 2048
#define NEXP 64
#define REFINE_TAU 4e-3f
#define NCHK 16                    // 16 chunks of 128 k
#define NBLK (T_TOKENS / 16)       // 1024 blocks, 16 tokens each

typedef _Float16 f16x8 __attribute__((ext_vector_type(8)));
typedef float f32x4 __attribute__((ext_vector_type(4)));

__device__ __forceinline__ void gload_lds16(const void* g, void* l) {
    __builtin_amdgcn_global_load_lds(
        (const __attribute__((address_space(1))) void*)g,
        (__attribute__((address_space(3))) void*)l, 16, 0, 0);
}

// ---------------- Kernel 0: W fp32 -> fp16 fragment-ordered panel ----------------
// (r,k) -> pw[((g*64 + ks)*64 + lane)*8 + j], g=r>>4, ks=k>>5,
// lane=((k>>3)&3)*16 + (r&15), j=k&7.  (A-frag mapping, verified R4-R18.)
__global__ __launch_bounds__(256)
void prep_w(const float* __restrict__ W, _Float16* __restrict__ pw) {
    const int t  = blockIdx.x * 256 + threadIdx.x;   // 0..16383
    const int r  = t >> 8;
    const int kc = (t & 255) * 8;
    const float* wp = &W[(size_t)r * DDIM + kc];
    const float4 a = *(const float4*)wp;
    const float4 b = *(const float4*)(wp + 4);
    const float f[8] = { a.x, a.y, a.z, a.w, b.x, b.y, b.z, b.w };
    f16x8 h;
#pragma unroll
    for (int j = 0; j < 8; ++j) h[j] = (_Float16)f[j];
    const int g = r >> 4, ks = kc >> 5;
    const int lane = (((kc >> 3) & 3) << 4) + (r & 15);
    *(f16x8*)&pw[(((size_t)g * 64 + ks) * 64 + lane) * 8] = h;
}

// ---------------- Kernel 1: counted-vmcnt pipelined gate + fused top-2 ----------------
__device__ __forceinline__ bool better(double va, int ia, double vb, int ib) {
    return (va > vb) || (va == vb && ia < ib);
}

// fast wave-cooperative f64 dot (R16-verified)
__device__ __forceinline__ double dot_f64_fast(const float* __restrict__ xrow,
                                               const float* __restrict__ wr, int lane) {
    float4 xa[8], wa[8];
#pragma unroll
    for (int q = 0; q < 8; ++q) {
        xa[q] = *(const float4*)&xrow[q * 256 + lane * 4];
        wa[q] = *(const float4*)&wr[q * 256 + lane * 4];
    }
    double s0 = 0.0, s1 = 0.0, s2 = 0.0, s3 = 0.0;
#pragma unroll
    for (int q = 0; q < 8; ++q) {
        s0 = fma((double)xa[q].x, (double)wa[q].x, s0);
        s1 = fma((double)xa[q].y, (double)wa[q].y, s1);
        s2 = fma((double)xa[q].z, (double)wa[q].z, s2);
        s3 = fma((double)xa[q].w, (double)wa[q].w, s3);
    }
    double sd = (s0 + s1) + (s2 + s3);
#pragma unroll
    for (int off = 32; off >= 1; off >>= 1) sd += __shfl_xor(sd, off);
    return sd;
}

// asm load: fixed FIFO position (countable), registers forcibly live
#define GLD(dst, p) asm volatile("global_load_dwordx4 %0, %1, off" \
                                 : "=v"(dst) : "v"(p) : "memory")

// stage chunk c into buf c&3: wave w covers rows 4w..4w+3, two 1KB gload_lds (2 vmcnt ops)
#define STAGE(c) do { \
    gload_lds16(xs0 + (size_t)(c) * 512, (char*)&xa[0][0] + ((c) & 3) * 8192 + (4 * w) * 512); \
    gload_lds16(xs1 + (size_t)(c) * 512, (char*)&xa[0][0] + ((c) & 3) * 8192 + (4 * w + 2) * 512); \
} while (0)

// panel frags for chunk c (4 ksteps) into pf[c&1] (4 vmcnt ops)
#define GLDP(c) do { \
    GLD(pf[(c) & 1][0], pwp + ((size_t)(c) * 4 + 0) * 1024); \
    GLD(pf[(c) & 1][1], pwp + ((size_t)(c) * 4 + 1) * 1024); \
    GLD(pf[(c) & 1][2], pwp + ((size_t)(c) * 4 + 2) * 1024); \
    GLD(pf[(c) & 1][3], pwp + ((size_t)(c) * 4 + 3) * 1024); \
} while (0)

// counted wait + scheduler fence (rule #18)
#define WAITV(N) do { \
    asm volatile("s_waitcnt vmcnt(" #N ")" ::: "memory"); \
    __builtin_amdgcn_sched_barrier(0); \
} while (0)

#define COMPUTE(c) do { \
    const char* xb_ = (const char*)&xa[0][0] + ((c) & 3) * 8192; \
    _Pragma("unroll") \
    for (int ks_ = 0; ks_ < 4; ++ks_) { \
        const int col_ = ks_ * 128 + ((lane >> 4) << 5); \
        const f32x4 v0_ = *(const f32x4*)(xb_ + rbase + ((col_)      ^ rswz)); \
        const f32x4 v1_ = *(const f32x4*)(xb_ + rbase + ((col_ + 16) ^ rswz)); \
        f16x8 af_; \
        af_[0] = (_Float16)v0_[0]; af_[1] = (_Float16)v0_[1]; \
        af_[2] = (_Float16)v0_[2]; af_[3] = (_Float16)v0_[3]; \
        af_[4] = (_Float16)v1_[0]; af_[5] = (_Float16)v1_[1]; \
        af_[6] = (_Float16)v1_[2]; af_[7] = (_Float16)v1_[3]; \
        acc = __builtin_amdgcn_mfma_f32_16x16x32_f16( \
            __builtin_bit_cast(f16x8, pf[(c) & 1][ks_]), af_, acc, 0, 0, 0); \
    } \
} while (0)

#define BAR() do { __builtin_amdgcn_s_barrier(); __builtin_amdgcn_sched_barrier(0); } while (0)

__global__ __launch_bounds__(256)
void gate_fused(const float* __restrict__ x,
                const _Float16* __restrict__ pw,
                const float* __restrict__ W,
                float* __restrict__ out) {
    __shared__ float xa[4][2048];     // 4 x 8 KB ring: 16 rows x 512B, swizzled content
    __shared__ float lg[16][68];      // logits [token][expert], padded

    const int tid  = threadIdx.x;
    const int lane = tid & 63;
    const int w    = tid >> 6;        // expert group 0..3
    const int tokb = blockIdx.x * 16;

    // ---- staging source (per-lane, pre-swizzled column; verified R17 involution) ----
    const int r0 = 4 * w + (lane >> 5);
    const int r1 = 4 * w + 2 + (lane >> 5);
    const int v0 = ((lane & 31) * 16) ^ ((r0 & 7) << 4);
    const int v1 = ((lane & 31) * 16) ^ ((r1 & 7) << 4);
    const char* xs0 = (const char*)x + (size_t)(tokb + r0) * (DDIM * 4) + v0;
    const char* xs1 = (const char*)x + (size_t)(tokb + r1) * (DDIM * 4) + v1;

    // panel per-lane byte base (R19 BUG FIX: wave slice stride is 64 frags x 1KB = 65536 B,
    // matching prep_w layout (((w*64 + q)*64 + lane)*8 shorts = w*65536 + q*1024 + lane*16 B)
    const char* pwp = (const char*)pw + (size_t)w * 65536 + (size_t)lane * 16;

    // frag-read geometry (verified R17)
    const int rbase = (lane & 15) * 512;
    const int rswz  = (lane & 7) << 4;

    float4 pf[2][4];                  // panel frags, asm-live
    f32x4 acc = { 0.f, 0.f, 0.f, 0.f };

    // prologue FIFO: S0(2) S1(2) S2(2) P0(4) P1(4)
    STAGE(0); STAGE(1); STAGE(2);
    GLDP(0);  GLDP(1);

    // N table derived from FIFO: {4, 6 x13, 4, 0}
    WAITV(4); BAR(); COMPUTE(0);  BAR(); STAGE(3);  GLDP(2);
    WAITV(6); BAR(); COMPUTE(1);  BAR(); STAGE(4);  GLDP(3);
    WAITV(6); BAR(); COMPUTE(2);  BAR(); STAGE(5);  GLDP(4);
    WAITV(6); BAR(); COMPUTE(3);  BAR(); STAGE(6);  GLDP(5);
    WAITV(6); BAR(); COMPUTE(4);  BAR(); STAGE(7);  GLDP(6);
    WAITV(6); BAR(); COMPUTE(5);  BAR(); STAGE(8);  GLDP(7);
    WAITV(6); BAR(); COMPUTE(6);  BAR(); STAGE(9);  GLDP(8);
    WAITV(6); BAR(); COMPUTE(7);  BAR(); STAGE(10); GLDP(9);
    WAITV(6); BAR(); COMPUTE(8);  BAR(); STAGE(11); GLDP(10);
    WAITV(6); BAR(); COMPUTE(9);  BAR(); STAGE(12); GLDP(11);
    WAITV(6); BAR(); COMPUTE(10); BAR(); STAGE(13); GLDP(12);
    WAITV(6); BAR(); COMPUTE(11); BAR(); STAGE(14); GLDP(13);
    WAITV(6); BAR(); COMPUTE(12); BAR(); STAGE(15); GLDP(14);
    WAITV(6); BAR(); COMPUTE(13); BAR();            GLDP(15);
    WAITV(4); BAR(); COMPUTE(14); BAR();
    WAITV(0); BAR(); COMPUTE(15);

    // ---- logits -> LDS (C layout verified: token=lane&15, expert=(lane>>4)*4+j + w*16) ----
    *(f32x4*)&lg[lane & 15][w * 16 + ((lane >> 4) << 2)] = acc;
    __syncthreads();

    // ---- fused epilogue: wave w owns 4 tokens (verified structure + fast refine) ----
    float* __restrict__ outw = out;
    float* __restrict__ outi = out + (size_t)T_TOKENS * 2;

#pragma unroll 1
    for (int t = 0; t < 4; ++t) {
        const int lt  = w * 4 + t;
        const int tok = tokb + lt;
        const float l = lg[lt][lane];

        float v1v = l; int i1 = lane;
#pragma unroll
        for (int off = 32; off >= 1; off >>= 1) {
            const float ov = __shfl_xor(v1v, off);
            const int   oi = __shfl_xor(i1, off);
            if (ov > v1v || (ov == v1v && oi < i1)) { v1v = ov; i1 = oi; }
        }
        float v2v = (lane == i1) ? -INFINITY : l; int i2 = lane;
#pragma unroll
        for (int off = 32; off >= 1; off >>= 1) {
            const float ov = __shfl_xor(v2v, off);
            const int   oi = __shfl_xor(i2, off);
            if (ov > v2v || (ov == v2v && oi < i2)) { v2v = ov; i2 = oi; }
        }
        float v3v = (lane == i1 || lane == i2) ? -INFINITY : l; int i3 = lane;
#pragma unroll
        for (int off = 32; off >= 1; off >>= 1) {
            const float ov = __shfl_xor(v3v, off);
            const int   oi = __shfl_xor(i3, off);
            if (ov > v3v || (ov == v3v && oi < i3)) { v3v = ov; i3 = oi; }
        }

        const float p = expf(l - v1v);
        float s = p;
#pragma unroll
        for (int off = 32; off >= 1; off >>= 1) s += __shfl_xor(s, off);

        int iA = i1, iB = i2;
        if ((v1v - v2v) < REFINE_TAU || (v2v - v3v) < REFINE_TAU) {
            const float* __restrict__ xrow = x + (size_t)tok * DDIM;
            double La = dot_f64_fast(xrow, W + (size_t)i1 * DDIM, lane);
            double Lb = dot_f64_fast(xrow, W + (size_t)i2 * DDIM, lane);
            double Lc = dot_f64_fast(xrow, W + (size_t)i3 * DDIM, lane);
            int ia = i1, ib = i2, ic = i3;
            if (!better(La, ia, Lb, ib)) { double tv = La; La = Lb; Lb = tv; int ti = ia; ia = ib; ib = ti; }
            if (!better(Lb, ib, Lc, ic)) { double tv = Lb; Lb = Lc; Lc = tv; int ti = ib; ib = ic; ic = ti; }
            if (!better(La, ia, Lb, ib)) { double tv = La; La = Lb; Lb = tv; int ti = ia; ia = ib; ib = ti; }
            iA = ia; iB = ib;
        }

        const float pA = __shfl(p, iA);
        const float pB = __shfl(p, iB);
        const float pa_ = pA / s;
        const float pb_ = pB / s;
        const float inv = 1.0f / (pa_ + pb_ + 1e-9f);

        if (lane == 0) {
            const size_t tg2 = (size_t)tok;
            outw[tg2 * 2]     = pa_ * inv;
            outw[tg2 * 2 + 1] = pb_ * inv;
            outi[tg2 * 2]     = (float)iA;
            outi[tg2 * 2 + 1] = (float)iB;
        }
    }
}

extern "C" void kernel_launch(void* const* d_in, const int* in_sizes, int n_in,
                              void* d_out, int out_size, void* d_ws, size_t ws_size,
                              hipStream_t stream) {
    const float* x = (const float*)d_in[0];
    const float* W = (const float*)d_in[1];
    float* out = (float*)d_out;
    _Float16* pw = (_Float16*)d_ws;                 // 256 KB fp16 frag panel

    prep_w<<<NEXP * DDIM / 8 / 256, 256, 0, stream>>>(W, pw);
    gate_fused<<<NBLK, 256, 0, stream>>>(x, pw, W, out);
}

// Round 22
// 52.576 us; speedup vs baseline: 1.1205x; 1.0243x over previous
//
#include <hip/hip_runtime.h>
#include <hip/hip_bf16.h>
#include <hip/hip_fp16.h>
#include <math.h>

#define T_TOKENS 16384
#define DDIM 2048
#define NEXP 64
#define REFINE_TAU 4e-3f
#define NCHK 16                    // 16 chunks of 128 k
#define NBLK (T_TOKENS / 16)       // 1024 blocks, 16 tokens each

typedef _Float16 f16x8 __attribute__((ext_vector_type(8)));
typedef float f32x4 __attribute__((ext_vector_type(4)));

__device__ __forceinline__ void gload_lds16(const void* g, void* l) {
    __builtin_amdgcn_global_load_lds(
        (const __attribute__((address_space(1))) void*)g,
        (__attribute__((address_space(3))) void*)l, 16, 0, 0);
}

// ---------------- Kernel 0: W fp32 -> fp16 fragment-ordered panel ----------------
// (r,k) -> pw[((g*64 + ks)*64 + lane)*8 + j], g=r>>4, ks=k>>5,
// lane=((k>>3)&3)*16 + (r&15), j=k&7.  (A-frag mapping, verified R4-R20.)
__global__ __launch_bounds__(256)
void prep_w(const float* __restrict__ W, _Float16* __restrict__ pw) {
    const int t  = blockIdx.x * 256 + threadIdx.x;   // 0..16383
    const int r  = t >> 8;
    const int kc = (t & 255) * 8;
    const float* wp = &W[(size_t)r * DDIM + kc];
    const float4 a = *(const float4*)wp;
    const float4 b = *(const float4*)(wp + 4);
    const float f[8] = { a.x, a.y, a.z, a.w, b.x, b.y, b.z, b.w };
    f16x8 h;
#pragma unroll
    for (int j = 0; j < 8; ++j) h[j] = (_Float16)f[j];
    const int g = r >> 4, ks = kc >> 5;
    const int lane = (((kc >> 3) & 3) << 4) + (r & 15);
    *(f16x8*)&pw[(((size_t)g * 64 + ks) * 64 + lane) * 8] = h;
}

// ---------------- Kernel 1: single-barrier counted-vmcnt gate + fused top-2 ----------------
__device__ __forceinline__ bool better(double va, int ia, double vb, int ib) {
    return (va > vb) || (va == vb && ia < ib);
}

// fast wave-cooperative f64 dot (R16-verified)
__device__ __forceinline__ double dot_f64_fast(const float* __restrict__ xrow,
                                               const float* __restrict__ wr, int lane) {
    float4 xa[8], wa[8];
#pragma unroll
    for (int q = 0; q < 8; ++q) {
        xa[q] = *(const float4*)&xrow[q * 256 + lane * 4];
        wa[q] = *(const float4*)&wr[q * 256 + lane * 4];
    }
    double s0 = 0.0, s1 = 0.0, s2 = 0.0, s3 = 0.0;
#pragma unroll
    for (int q = 0; q < 8; ++q) {
        s0 = fma((double)xa[q].x, (double)wa[q].x, s0);
        s1 = fma((double)xa[q].y, (double)wa[q].y, s1);
        s2 = fma((double)xa[q].z, (double)wa[q].z, s2);
        s3 = fma((double)xa[q].w, (double)wa[q].w, s3);
    }
    double sd = (s0 + s1) + (s2 + s3);
#pragma unroll
    for (int off = 32; off >= 1; off >>= 1) sd += __shfl_xor(sd, off);
    return sd;
}

// asm load: fixed FIFO position (countable), registers forcibly live
#define GLD(dst, p) asm volatile("global_load_dwordx4 %0, %1, off" \
                                 : "=v"(dst) : "v"(p) : "memory")

// stage chunk c into ring buf c&3 (2 vmcnt ops/wave)
#define STAGE(c) do { \
    gload_lds16(xs0 + (size_t)(c) * 512, (char*)&xa[0][0] + ((c) & 3) * 8192 + (4 * w) * 512); \
    gload_lds16(xs1 + (size_t)(c) * 512, (char*)&xa[0][0] + ((c) & 3) * 8192 + (4 * w + 2) * 512); \
} while (0)

// panel frags for chunk c into pf[c&1] (4 vmcnt ops)
#define GLDP(c) do { \
    GLD(pf[(c) & 1][0], pwp + ((size_t)(c) * 4 + 0) * 1024); \
    GLD(pf[(c) & 1][1], pwp + ((size_t)(c) * 4 + 1) * 1024); \
    GLD(pf[(c) & 1][2], pwp + ((size_t)(c) * 4 + 2) * 1024); \
    GLD(pf[(c) & 1][3], pwp + ((size_t)(c) * 4 + 3) * 1024); \
} while (0)

// counted wait + scheduler fence (rule #18)
#define WAITV(N) do { \
    asm volatile("s_waitcnt vmcnt(" #N ")" ::: "memory"); \
    __builtin_amdgcn_sched_barrier(0); \
} while (0)

// barrier + hoist fence (R20-proven safe form)
#define BAR() do { __builtin_amdgcn_s_barrier(); __builtin_amdgcn_sched_barrier(0); } while (0)

#define COMPUTE(c) do { \
    const char* xb_ = (const char*)&xa[0][0] + ((c) & 3) * 8192; \
    _Pragma("unroll") \
    for (int ks_ = 0; ks_ < 4; ++ks_) { \
        const int col_ = ks_ * 128 + ((lane >> 4) << 5); \
        const f32x4 v0_ = *(const f32x4*)(xb_ + rbase + ((col_)      ^ rswz)); \
        const f32x4 v1_ = *(const f32x4*)(xb_ + rbase + ((col_ + 16) ^ rswz)); \
        f16x8 af_; \
        af_[0] = (_Float16)v0_[0]; af_[1] = (_Float16)v0_[1]; \
        af_[2] = (_Float16)v0_[2]; af_[3] = (_Float16)v0_[3]; \
        af_[4] = (_Float16)v1_[0]; af_[5] = (_Float16)v1_[1]; \
        af_[6] = (_Float16)v1_[2]; af_[7] = (_Float16)v1_[3]; \
        acc = __builtin_amdgcn_mfma_f32_16x16x32_f16( \
            __builtin_bit_cast(f16x8, pf[(c) & 1][ks_]), af_, acc, 0, 0, 0); \
    } \
} while (0)

// iter: WAITV(N) -> BAR -> COMPUTE(c)   (one barrier per chunk)
#define ITER(c, N) do { WAITV(N); BAR(); COMPUTE(c); } while (0)

__global__ __launch_bounds__(256)
void gate_fused(const float* __restrict__ x,
                const _Float16* __restrict__ pw,
                const float* __restrict__ W,
                float* __restrict__ out) {
    __shared__ float xa[4][2048];     // 4 x 8 KB ring; logits overlay xa[0] after main loop

    const int tid  = threadIdx.x;
    const int lane = tid & 63;
    const int w    = tid >> 6;        // expert group 0..3
    const int tokb = blockIdx.x * 16;

    // ---- staging source (per-lane, pre-swizzled column; verified R17 involution) ----
    const int r0 = 4 * w + (lane >> 5);
    const int r1 = 4 * w + 2 + (lane >> 5);
    const int v0 = ((lane & 31) * 16) ^ ((r0 & 7) << 4);
    const int v1 = ((lane & 31) * 16) ^ ((r1 & 7) << 4);
    const char* xs0 = (const char*)x + (size_t)(tokb + r0) * (DDIM * 4) + v0;
    const char* xs1 = (const char*)x + (size_t)(tokb + r1) * (DDIM * 4) + v1;

    // panel per-lane byte base (R20-verified): wave slice stride 65536 B
    const char* pwp = (const char*)pw + (size_t)w * 65536 + (size_t)lane * 16;

    // frag-read geometry (verified R17)
    const int rbase = (lane & 15) * 512;
    const int rswz  = (lane & 7) << 4;

    float4 pf[2][4];                  // panel frags, asm-live
    f32x4 acc = { 0.f, 0.f, 0.f, 0.f };

    // prologue FIFO: S0(2) P0(4) S1(2) P1(4) S2(2) = 14
    STAGE(0); GLDP(0); STAGE(1); GLDP(1); STAGE(2);

    // Corrected vmcnt table from the true FIFO (post-iter order is S-then-P, so
    // at ITER(c>=2) FIFO = [S(c), S(c+1), P(c), S(c+2), P(c+1)]; remainder
    // after P(c) = 6):  I0:8, I1:8, I2..13:6, I14:4, I15:0.
    ITER(0, 8);  STAGE(3);  GLDP(2);
    ITER(1, 8);  STAGE(4);  GLDP(3);
    ITER(2, 6);  STAGE(5);  GLDP(4);
    ITER(3, 6);  STAGE(6);  GLDP(5);
    ITER(4, 6);  STAGE(7);  GLDP(6);
    ITER(5, 6);  STAGE(8);  GLDP(7);
    ITER(6, 6);  STAGE(9);  GLDP(8);
    ITER(7, 6);  STAGE(10); GLDP(9);
    ITER(8, 6);  STAGE(11); GLDP(10);
    ITER(9, 6);  STAGE(12); GLDP(11);
    ITER(10, 6); STAGE(13); GLDP(12);
    ITER(11, 6); STAGE(14); GLDP(13);
    ITER(12, 6); STAGE(15); GLDP(14);
    ITER(13, 6);            GLDP(15);
    ITER(14, 4);
    ITER(15, 0);

    // ---- logits overlay xa[0] (all xa reads done); barrier first ----
    __syncthreads();
    float (*lg)[68] = reinterpret_cast<float(*)[68]>(&xa[0][0]);   // 4.35 KB
    *(f32x4*)&lg[lane & 15][w * 16 + ((lane >> 4) << 2)] = acc;
    __syncthreads();

    // ---- fused epilogue: wave w owns 4 tokens (verified structure + fast refine) ----
    float* __restrict__ outw = out;
    float* __restrict__ outi = out + (size_t)T_TOKENS * 2;

#pragma unroll 1
    for (int t = 0; t < 4; ++t) {
        const int lt  = w * 4 + t;
        const int tok = tokb + lt;
        const float l = lg[lt][lane];

        float v1v = l; int i1 = lane;
#pragma unroll
        for (int off = 32; off >= 1; off >>= 1) {
            const float ov = __shfl_xor(v1v, off);
            const int   oi = __shfl_xor(i1, off);
            if (ov > v1v || (ov == v1v && oi < i1)) { v1v = ov; i1 = oi; }
        }
        float v2v = (lane == i1) ? -INFINITY : l; int i2 = lane;
#pragma unroll
        for (int off = 32; off >= 1; off >>= 1) {
            const float ov = __shfl_xor(v2v, off);
            const int   oi = __shfl_xor(i2, off);
            if (ov > v2v || (ov == v2v && oi < i2)) { v2v = ov; i2 = oi; }
        }
        float v3v = (lane == i1 || lane == i2) ? -INFINITY : l; int i3 = lane;
#pragma unroll
        for (int off = 32; off >= 1; off >>= 1) {
            const float ov = __shfl_xor(v3v, off);
            const int   oi = __shfl_xor(i3, off);
            if (ov > v3v || (ov == v3v && oi < i3)) { v3v = ov; i3 = oi; }
        }

        const float p = expf(l - v1v);
        float s = p;
#pragma unroll
        for (int off = 32; off >= 1; off >>= 1) s += __shfl_xor(s, off);

        int iA = i1, iB = i2;
        if ((v1v - v2v) < REFINE_TAU || (v2v - v3v) < REFINE_TAU) {
            const float* __restrict__ xrow = x + (size_t)tok * DDIM;
            double La = dot_f64_fast(xrow, W + (size_t)i1 * DDIM, lane);
            double Lb = dot_f64_fast(xrow, W + (size_t)i2 * DDIM, lane);
            double Lc = dot_f64_fast(xrow, W + (size_t)i3 * DDIM, lane);
            int ia = i1, ib = i2, ic = i3;
            if (!better(La, ia, Lb, ib)) { double tv = La; La = Lb; Lb = tv; int ti = ia; ia = ib; ib = ti; }
            if (!better(Lb, ib, Lc, ic)) { double tv = Lb; Lb = Lc; Lc = tv; int ti = ib; ib = ic; ic = ti; }
            if (!better(La, ia, Lb, ib)) { double tv = La; La = Lb; Lb = tv; int ti = ia; ia = ib; ib = ti; }
            iA = ia; iB = ib;
        }

        const float pA = __shfl(p, iA);
        const float pB = __shfl(p, iB);
        const float pa_ = pA / s;
        const float pb_ = pB / s;
        const float inv = 1.0f / (pa_ + pb_ + 1e-9f);

        if (lane == 0) {
            const size_t tg2 = (size_t)tok;
            outw[tg2 * 2]     = pa_ * inv;
            outw[tg2 * 2 + 1] = pb_ * inv;
            outi[tg2 * 2]     = (float)iA;
            outi[tg2 * 2 + 1] = (float)iB;
        }
    }
}

extern "C" void kernel_launch(void* const* d_in, const int* in_sizes, int n_in,
                              void* d_out, int out_size, void* d_ws, size_t ws_size,
                              hipStream_t stream) {
    const float* x = (const float*)d_in[0];
    const float* W = (const float*)d_in[1];
    float* out = (float*)d_out;
    _Float16* pw = (_Float16*)d_ws;                 // 256 KB fp16 frag panel

    prep_w<<<NEXP * DDIM / 8 / 256, 256, 0, stream>>>(W, pw);
    gate_fused<<<NBLK, 256, 0, stream>>>(x, pw, W, out);
}